// Round 8
// baseline (808.608 us; speedup 1.0000x reference)
//
#include <hip/hip_runtime.h>
#include <math.h>

// Problem constants: B=8, C=256, H=W=128
#define PIX 16384                       // H*W
#define TSZ ((size_t)33554432)          // 8*256*16384 elements per tensor

typedef __attribute__((ext_vector_type(8))) short  short8;   // 8 x bf16 (4 VGPRs)
typedef __attribute__((ext_vector_type(4))) float  float4v;
typedef __attribute__((ext_vector_type(4))) unsigned int uint4v;
typedef __attribute__((ext_vector_type(2))) unsigned int uint2v;

__device__ __forceinline__ unsigned short f2bf(float x) {
  unsigned int u = __float_as_uint(x);
  u += 0x7fffu + ((u >> 16) & 1u);      // round-to-nearest-even
  return (unsigned short)(u >> 16);
}
__device__ __forceinline__ float bf2f(unsigned short h) {
  return __uint_as_float(((unsigned int)h) << 16);
}
// pack two fp32 -> (bf16(hi)<<16)|bf16(lo) via v_perm_b32
__device__ __forceinline__ unsigned int pack_bf2(float lo, float hi) {
  unsigned int ul = __float_as_uint(lo); ul += 0x7fffu + ((ul >> 16) & 1u);
  unsigned int uh = __float_as_uint(hi); uh += 0x7fffu + ((uh >> 16) & 1u);
  return __builtin_amdgcn_perm(uh, ul, 0x07060302u);  // [ul.b2,ul.b3,uh.b2,uh.b3]
}

#define SB0   __builtin_amdgcn_sched_barrier(0)
#define BARR  __builtin_amdgcn_s_barrier()
#define LGKM0 asm volatile("s_waitcnt lgkmcnt(0)" ::: "memory")
#define VMC(n) asm volatile("s_waitcnt vmcnt(" #n ")" ::: "memory")

// ---------------------------------------------------------------------------
// Kernel 0: weights -> bf16, PACKED for lane-linear 1KB wave loads.
// Layout (shorts): wpk[g][i=kstep(8)][wv(4)][im(4)][lane(64)][e(8)]
//   lane=(q<<4)|col;  m = wv*64+im*16+col;  k = i*32+q*8+e
// Conv order: 0=FF(wf), 1=GG(wg), 2=EE(we), 3=HH(wh)
// ---------------------------------------------------------------------------
__global__ __launch_bounds__(256) void k_prep(const float* __restrict__ we,
                                              const float* __restrict__ wf,
                                              const float* __restrict__ wg,
                                              const float* __restrict__ wh,
                                              unsigned short* __restrict__ wbf) {
  int idx = blockIdx.x * 256 + threadIdx.x;      // 0 .. 262143
  int g = idx >> 16, within = idx & 65535;
  const float* src = (g == 0) ? wf : (g == 1) ? wg : (g == 2) ? we : wh;
  int e    = within & 7;
  int lane = (within >> 3) & 63;
  int im   = (within >> 9) & 3;
  int wv   = (within >> 11) & 3;
  int i    = within >> 13;
  int col = lane & 15, q = lane >> 4;
  int m = wv * 64 + im * 16 + col;
  int k = i * 32 + q * 8 + e;
  wbf[idx] = f2bf(src[m * 256 + k]);
}

// ---------------------------------------------------------------------------
// Kernel 1: 7x7 patch stats (zero-padded box sums), normalization, adain.
// (R7 structure kept: no xs LDS, global-direct reads, (256,4), 48 VGPR.)
// Output TILED: xcm[tens][b][pt(256)][k=c(256)][px(64)] bf16.
// ---------------------------------------------------------------------------
__global__ __launch_bounds__(256, 4) void k_stats(const float* __restrict__ front,
                                                  const float* __restrict__ back,
                                                  unsigned short* __restrict__ xcm) {
  int blk = blockIdx.x;
  int s   = blk & 7;            // strip (16 rows)
  int c   = (blk >> 3) & 255;
  int b   = blk >> 11;
  int t   = threadIdx.x;
  int r0  = s * 16;

  __shared__ float2 vspD[16 * 137];        // 17.54 KB; cols 3..130 = -3..130 data, pads zeroed

  size_t planeOff = ((size_t)(b * 256 + c)) * PIX;

  float meanR[8], sdR[8];       // back stats, phase0 -> phase1 carry

  #pragma unroll 1
  for (int phase = 0; phase < 2; ++phase) {     // 0 = back, 1 = front
    const float* src = (phase == 0 ? back : front) + planeOff;
    // ---- vertical 7-tap sliding box sums: global -> registers -> vspD ----
    {
      int col = t & 127;
      int rg  = (t >> 7) * 8;                    // 8 output rows per thread
      const float* colp = src + col;
      float xv[14];                              // rows r0+rg-3 .. r0+rg+10
      #pragma unroll
      for (int j = 0; j < 14; ++j) {
        int g = r0 + rg - 3 + j;
        float v = 0.f;
        if (g >= 0 && g < 128) v = colp[g * 128];
        xv[j] = v;
      }
      float sm = 0.f, s2 = 0.f;
      #pragma unroll
      for (int j = 0; j < 7; ++j) { sm += xv[j]; s2 = fmaf(xv[j], xv[j], s2); }
      vspD[rg * 137 + col + 3] = make_float2(sm, s2);
      #pragma unroll
      for (int o = 1; o < 8; ++o) {
        float vn = xv[o + 6], vo = xv[o - 1];
        sm += vn - vo;
        s2 += vn * vn - vo * vo;
        vspD[(rg + o) * 137 + col + 3] = make_float2(sm, s2);
      }
      // zero pads: array cols 0,1,2 and 131,132,133 for all 16 rows
      if (t < 96) {
        int rr = t & 15;
        int pc = t >> 4;                         // 0..5
        int ac = (pc < 3) ? pc : 128 + pc;       // 0,1,2,131,132,133
        vspD[rr * 137 + ac] = make_float2(0.f, 0.f);
      }
    }
    LGKM0; BARR;
    // ---- horizontal 7-tap sliding window + finalize + DIRECT stores ----
    {
      int r  = t & 15;
      int c0 = (t >> 4) * 8;                     // 8 output cols per thread
      float2 w[14];
      #pragma unroll
      for (int i = 0; i < 14; ++i) w[i] = vspD[r * 137 + c0 + i];
      // center x values, re-read from global (L1-hot: just fetched above)
      float4v x0 = *(const float4v*)(src + (r0 + r) * 128 + c0);
      float4v x1 = *(const float4v*)(src + (r0 + r) * 128 + c0 + 4);
      float xc[8] = {x0[0], x0[1], x0[2], x0[3], x1[0], x1[1], x1[2], x1[3]};
      float sm = 0.f, s2 = 0.f;
      #pragma unroll
      for (int i = 0; i < 7; ++i) { sm += w[i].x; s2 += w[i].y; }
      float nrmv[8], hv[8];
      #pragma unroll
      for (int o = 0; o < 8; ++o) {
        float mean = sm * (1.f / 49.f);
        float var  = (s2 - sm * mean) * (1.f / 48.f);   // (s2 - s^2/49)/48
        var = var > 0.f ? var : 0.f;
        float sd = __builtin_amdgcn_sqrtf(var);
        float x  = xc[o];
        float nrm = (x - mean) * __builtin_amdgcn_rcpf(sd + 1e-8f);
        if (phase == 0) { meanR[o] = mean; sdR[o] = sd; hv[o] = x; }
        else            { hv[o] = nrm * sdR[o] + meanR[o]; }
        nrmv[o] = nrm;
        if (o < 7) { sm += w[o + 7].x - w[o].x; s2 += w[o + 7].y - w[o].y; }
      }
      uint4v nv  = (uint4v){pack_bf2(nrmv[0], nrmv[1]), pack_bf2(nrmv[2], nrmv[3]),
                            pack_bf2(nrmv[4], nrmv[5]), pack_bf2(nrmv[6], nrmv[7])};
      uint4v hvv = (uint4v){pack_bf2(hv[0], hv[1]), pack_bf2(hv[2], hv[3]),
                            pack_bf2(hv[4], hv[5]), pack_bf2(hv[6], hv[7])};
      // tiled store: p -> (pt=p>>6, pxi=p&63); addr = ((b*256+pt)*256+c)*64+pxi
      int p = (r0 + r) * 128 + c0;
      size_t gb2 = (((size_t)(b * 256 + (p >> 6))) * 256 + c) * 64 + (p & 63);
      int tn0 = (phase == 0) ? 1 : 0;
      int tn1 = (phase == 0) ? 3 : 2;
      *(uint4v*)(xcm + (size_t)tn0 * TSZ + gb2) = nv;
      *(uint4v*)(xcm + (size_t)tn1 * TSZ + gb2) = hvv;
    }
    LGKM0; BARR;   // all vspD reads done; next phase may overwrite
  }
}

// ---------------------------------------------------------------------------
// GEMM machinery (R3's counted-vmcnt 5-buffer pipeline, packed operands).
// ---------------------------------------------------------------------------
__device__ __forceinline__ void stage_tile(const unsigned short* __restrict__ Xt,
                                           int k0, int t,
                                           unsigned short* dst) {
  // LDS 16B-chunk t holds subtile element: k = (t>>5)*4 + ((t&7)>>1),
  // px = ((t>>3)&3)*16 + (t&1)*8.  Source tile is contiguous [k][px] 4KB.
  int kk = ((t >> 5) << 2) + ((t & 7) >> 1);
  int px = (((t >> 3) & 3) << 4) + ((t & 1) << 3);
  const unsigned short* src = Xt + (size_t)(k0 << 6) + (kk << 6) + px;
  typedef const __attribute__((address_space(1))) unsigned int GUI;
  typedef __attribute__((address_space(3))) unsigned int LUI;
  __builtin_amdgcn_global_load_lds((GUI*)(unsigned long long)src,
                                   (LUI*)(unsigned)(unsigned long long)(dst + t * 8),
                                   16, 0, 0);
}

// packed weights: af[S][im] <- Wr + I*8192 + im*512  (lane-linear 1KB/instr)
#define LOADA(S, I) {                                           \
  af[S][0] = *(const short8*)(Wr + (I) * 8192 + 0 * 512);       \
  af[S][1] = *(const short8*)(Wr + (I) * 8192 + 1 * 512);       \
  af[S][2] = *(const short8*)(Wr + (I) * 8192 + 2 * 512);       \
  af[S][3] = *(const short8*)(Wr + (I) * 8192 + 3 * 512); }

#define TR8(O0,O1,O2,O3,O4,O5,O6,O7)                                              \
  asm volatile("ds_read_b64_tr_b16 %0, %1 offset:" #O0 : "=v"(r0) : "v"(tra));    \
  asm volatile("ds_read_b64_tr_b16 %0, %1 offset:" #O1 : "=v"(r1) : "v"(tra));    \
  asm volatile("ds_read_b64_tr_b16 %0, %1 offset:" #O2 : "=v"(r2) : "v"(tra));    \
  asm volatile("ds_read_b64_tr_b16 %0, %1 offset:" #O3 : "=v"(r3) : "v"(tra));    \
  asm volatile("ds_read_b64_tr_b16 %0, %1 offset:" #O4 : "=v"(r4) : "v"(tra));    \
  asm volatile("ds_read_b64_tr_b16 %0, %1 offset:" #O5 : "=v"(r5) : "v"(tra));    \
  asm volatile("ds_read_b64_tr_b16 %0, %1 offset:" #O6 : "=v"(r6) : "v"(tra));    \
  asm volatile("ds_read_b64_tr_b16 %0, %1 offset:" #O7 : "=v"(r7) : "v"(tra));

#define DOMFMA(MS) {                                                        \
  union BU { unsigned u[4]; short8 s; } bu0, bu1, bu2, bu3;                 \
  bu0.u[0]=r0[0]; bu0.u[1]=r0[1]; bu0.u[2]=r1[0]; bu0.u[3]=r1[1];           \
  bu1.u[0]=r2[0]; bu1.u[1]=r2[1]; bu1.u[2]=r3[0]; bu1.u[3]=r3[1];           \
  bu2.u[0]=r4[0]; bu2.u[1]=r4[1]; bu2.u[2]=r5[0]; bu2.u[3]=r5[1];           \
  bu3.u[0]=r6[0]; bu3.u[1]=r6[1]; bu3.u[2]=r7[0]; bu3.u[3]=r7[1];           \
  short8 bv0 = bu0.s, bv1 = bu1.s, bv2 = bu2.s, bv3 = bu3.s;                \
  _Pragma("unroll")                                                         \
  for (int im = 0; im < 4; ++im) {                                          \
    acc[0][im] = __builtin_amdgcn_mfma_f32_16x16x32_bf16(af[MS][im], bv0, acc[0][im], 0, 0, 0); \
    acc[1][im] = __builtin_amdgcn_mfma_f32_16x16x32_bf16(af[MS][im], bv1, acc[1][im], 0, 0, 0); \
    acc[2][im] = __builtin_amdgcn_mfma_f32_16x16x32_bf16(af[MS][im], bv2, acc[2][im], 0, 0, 0); \
    acc[3][im] = __builtin_amdgcn_mfma_f32_16x16x32_bf16(af[MS][im], bv3, acc[3][im], 0, 0, 0); \
  } }

// one K-step: optional stage (depth-3), optional A prefetch (2 ahead),
// counted vmcnt, barrier, tr-reads of buf i, MFMA.
#define GSTEP(VN, DOSTAGE, K0, SLOT, DOA, AS, AI, MS, O0,O1,O2,O3,O4,O5,O6,O7) \
  SB0;                                                                          \
  if (DOSTAGE) stage_tile(X, K0, t, xt + (SLOT) * 2048);                        \
  SB0;                                                                          \
  if (DOA) LOADA(AS, AI);                                                       \
  SB0;                                                                          \
  VMC(VN);                                                                      \
  SB0; BARR; SB0;                                                               \
  TR8(O0,O1,O2,O3,O4,O5,O6,O7);                                                 \
  LGKM0; SB0;                                                                   \
  DOMFMA(MS);

__device__ __forceinline__ void gemm_pipe(const unsigned short* __restrict__ X,
                                          const unsigned short* __restrict__ Wm,
                                          unsigned short* xt, unsigned xbase,
                                          int mbase, int lane, int t,
                                          float4v acc[4][4]) {
  unsigned tra = xbase + (unsigned)((((lane >> 4)) << 10) + ((lane & 15) << 3));
  // packed weights: Wr = Wm + wv*2048 + lane*8
  const unsigned short* __restrict__ Wr = Wm + ((mbase >> 6) << 11) + lane * 8;

  short8 af[3][4];
  uint2v r0, r1, r2, r3, r4, r5, r6, r7;

  #pragma unroll
  for (int in = 0; in < 4; ++in)
    #pragma unroll
    for (int im = 0; im < 4; ++im)
      acc[in][im] = (float4v){0.f, 0.f, 0.f, 0.f};

  // top barrier: all waves done reading slots of the previous gemm
  SB0; BARR; SB0;
  stage_tile(X,  0, t, xt + 0 * 2048);
  stage_tile(X, 32, t, xt + 1 * 2048);
  stage_tile(X, 64, t, xt + 2 * 2048);
  SB0;
  LOADA(0, 0);
  SB0;
  LOADA(1, 1);
  SB0;

  //     VN  st  K0  slot  A  AS AI MS   tr offsets (slot*4096 + subtile)
  GSTEP( 9,  1,  96,  3,   1, 2, 2, 0,      0,  512,  128,  640,  256,  768,  384,  896)
  GSTEP(10,  1, 128,  4,   1, 0, 3, 1,   4096, 4608, 4224, 4736, 4352, 4864, 4480, 4992)
  GSTEP(10,  1, 160,  0,   1, 1, 4, 2,   8192, 8704, 8320, 8832, 8448, 8960, 8576, 9088)
  GSTEP(10,  1, 192,  1,   1, 2, 5, 0,  12288,12800,12416,12928,12544,13056,12672,13184)
  GSTEP(10,  1, 224,  2,   1, 0, 6, 1,  16384,16896,16512,17024,16640,17152,16768,17280)
  GSTEP( 9,  0,   0,  0,   1, 1, 7, 2,      0,  512,  128,  640,  256,  768,  384,  896)
  GSTEP( 4,  0,   0,  0,   0, 0, 0, 0,   4096, 4608, 4224, 4736, 4352, 4864, 4480, 4992)
  GSTEP( 0,  0,   0,  0,   0, 0, 0, 1,   8192, 8704, 8320, 8832, 8448, 8960, 8576, 9088)
}

// ---------------------------------------------------------------------------
// Kernel 2a: FF/GG gemms -> cosine similarity S.
// R8: __launch_bounds__(256,4) -- 4 blocks/CU (was 2). The pipe is
// latency-bound (MfmaUtil ~12%, R2/R3 PMC); doubling resident blocks
// doubles independent pipelines per CU. VGPR fits: measured 116 <= 128.
// ---------------------------------------------------------------------------
__global__ __launch_bounds__(256, 4) void k_gemm1(const unsigned short* __restrict__ xcm,
                                                  const unsigned short* __restrict__ wbf,
                                                  const float* __restrict__ bFF,
                                                  const float* __restrict__ bGG,
                                                  float* __restrict__ Sout) {
  int blk  = blockIdx.x;
  int b    = blk >> 8;
  int pt   = blk & 255;
  int p0   = pt * 64;
  int t    = threadIdx.x;
  int wv   = t >> 6;
  int lane = t & 63;
  int q    = lane >> 4;
  int mbase = wv * 64;

  __shared__ __align__(16) unsigned short xt[5][2048];   // 20 KB: 5 X buffers
  __shared__ float sred[3 * 64];       // dot, |F|^2, |G|^2 per pixel
  if (t < 192) sred[t] = 0.f;
  __syncthreads();
  unsigned xbase = (unsigned)(unsigned long long)&xt[0][0];

  // contiguous X tile base for this (b, pt): xcm[tens][b][pt][k][px]
  const unsigned short* Xt = xcm + (((size_t)(b * 256 + pt)) << 14);

  float4v aF[4][4], aG[4][4];

  gemm_pipe(Xt + 0 * TSZ, wbf + 0 * 65536, &xt[0][0], xbase, mbase, lane, t, aF);
  gemm_pipe(Xt + 1 * TSZ, wbf + 1 * 65536, &xt[0][0], xbase, mbase, lane, t, aG);
  #pragma unroll
  for (int im = 0; im < 4; ++im) {
    float4v bvF = *(const float4v*)(bFF + mbase + im * 16 + q * 4);
    float4v bvG = *(const float4v*)(bGG + mbase + im * 16 + q * 4);
    #pragma unroll
    for (int in = 0; in < 4; ++in) { aF[in][im] += bvF; aG[in][im] += bvG; }
  }
  // cosine partials: lane-local over 16 m's, then quad shuffle, then LDS
  #pragma unroll
  for (int in = 0; in < 4; ++in) {
    float d = 0.f, nf = 0.f, ng = 0.f;
    #pragma unroll
    for (int im = 0; im < 4; ++im)
      #pragma unroll
      for (int r = 0; r < 4; ++r) {
        float f = aF[in][im][r], g = aG[in][im][r];
        d += f * g; nf += f * f; ng += g * g;
      }
    d  += __shfl_xor(d, 16);  d  += __shfl_xor(d, 32);
    nf += __shfl_xor(nf, 16); nf += __shfl_xor(nf, 32);
    ng += __shfl_xor(ng, 16); ng += __shfl_xor(ng, 32);
    if (lane < 16) {
      atomicAdd(&sred[0 * 64 + in * 16 + lane], d);
      atomicAdd(&sred[1 * 64 + in * 16 + lane], nf);
      atomicAdd(&sred[2 * 64 + in * 16 + lane], ng);
    }
  }
  __syncthreads();
  if (t < 64) {
    float d = sred[t], nf = sred[64 + t], ng = sred[128 + t];
    Sout[(size_t)b * PIX + p0 + t] = d / (sqrtf(nf) * sqrtf(ng));
  }
}

// ---------------------------------------------------------------------------
// Kernel 2b: EE/HH gemms fused with the blend: out = S_n*EE + (1-S_n)*HH.
// R8: __launch_bounds__(256,4) (same rationale as k_gemm1).
// ---------------------------------------------------------------------------
__global__ __launch_bounds__(256, 4) void k_gemm2(const unsigned short* __restrict__ xcm,
                                                  const unsigned short* __restrict__ wbf,
                                                  const float* __restrict__ bEE,
                                                  const float* __restrict__ bHH,
                                                  const float* __restrict__ S,
                                                  const float* __restrict__ mm,
                                                  float* __restrict__ out) {
  int blk  = blockIdx.x;
  int b    = blk >> 8;
  int pt   = blk & 255;
  int p0   = pt * 64;
  int t    = threadIdx.x;
  int wv   = t >> 6;
  int lane = t & 63;
  int col  = lane & 15;
  int q    = lane >> 4;
  int mbase = wv * 64;

  __shared__ __align__(16) unsigned short xt[5][2048];   // 20 KB: 5 X buffers
  unsigned xbase = (unsigned)(unsigned long long)&xt[0][0];

  const unsigned short* Xt = xcm + (((size_t)(b * 256 + pt)) << 14);

  float4v aE[4][4], aH[4][4];

  gemm_pipe(Xt + 2 * TSZ, wbf + 2 * 65536, &xt[0][0], xbase, mbase, lane, t, aE);
  gemm_pipe(Xt + 3 * TSZ, wbf + 3 * 65536, &xt[0][0], xbase, mbase, lane, t, aH);

  float mn = mm[b * 2], mx = mm[b * 2 + 1];
  float inv = 1.f / (mx - mn);
  float sn[4];
  #pragma unroll
  for (int in = 0; in < 4; ++in)
    sn[in] = (S[(size_t)b * PIX + p0 + in * 16 + col] - mn) * inv;

  #pragma unroll
  for (int im = 0; im < 4; ++im) {
    float4v bvE = *(const float4v*)(bEE + mbase + im * 16 + q * 4);
    float4v bvH = *(const float4v*)(bHH + mbase + im * 16 + q * 4);
    #pragma unroll
    for (int in = 0; in < 4; ++in)
      #pragma unroll
      for (int r = 0; r < 4; ++r) {
        int m = mbase + im * 16 + q * 4 + r;
        float e = aE[in][im][r] + bvE[r];
        float h = aH[in][im][r] + bvH[r];
        out[((size_t)(b * 256 + m)) * PIX + p0 + in * 16 + col] = h + sn[in] * (e - h);
      }
  }
}

// ---------------------------------------------------------------------------
// Kernel 3: per-batch min/max of S (one block per batch)
// ---------------------------------------------------------------------------
__global__ __launch_bounds__(256) void k_minmax(const float* __restrict__ S,
                                                float* __restrict__ mm) {
  int b = blockIdx.x, t = threadIdx.x;
  const float* sp = S + (size_t)b * PIX;
  float mn = 3.0e38f, mx = -3.0e38f;
  for (int i = t; i < PIX; i += 256) { float v = sp[i]; mn = fminf(mn, v); mx = fmaxf(mx, v); }
  #pragma unroll
  for (int o = 32; o >= 1; o >>= 1) {
    mn = fminf(mn, __shfl_xor(mn, o));
    mx = fmaxf(mx, __shfl_xor(mx, o));
  }
  __shared__ float smn[4], smx[4];
  if ((t & 63) == 0) { smn[t >> 6] = mn; smx[t >> 6] = mx; }
  __syncthreads();
  if (t == 0) {
    mn = fminf(fminf(smn[0], smn[1]), fminf(smn[2], smn[3]));
    mx = fmaxf(fmaxf(smx[0], smx[1]), fmaxf(smx[2], smx[3]));
    mm[b * 2] = mn; mm[b * 2 + 1] = mx;
  }
}

// ---------------------------------------------------------------------------
// Workspace layout (bytes):
//   0          : xcm   4 tensors bf16 (tiled)    = 268,435,456
//   268435456  : wbf   4x256x256 bf16 (packed)   =     524,288
//   268959744  : S     fp32 8x16384              =     524,288
//   269484032  : mm    fp32 8x2                  =          64
// total ~269.5 MB
// ---------------------------------------------------------------------------
extern "C" void kernel_launch(void* const* d_in, const int* in_sizes, int n_in,
                              void* d_out, int out_size, void* d_ws, size_t ws_size,
                              hipStream_t stream) {
  const float* front = (const float*)d_in[0];
  const float* back  = (const float*)d_in[1];
  // d_in[2] = mask (unused by reference)
  const float* we = (const float*)d_in[3];
  const float* be = (const float*)d_in[4];
  const float* wf = (const float*)d_in[5];
  const float* bf = (const float*)d_in[6];
  const float* wg = (const float*)d_in[7];
  const float* bg = (const float*)d_in[8];
  const float* wh = (const float*)d_in[9];
  const float* bh = (const float*)d_in[10];

  char* ws = (char*)d_ws;
  unsigned short* xcm  = (unsigned short*)(ws);
  unsigned short* wbf  = (unsigned short*)(ws + 268435456);
  float*          S    = (float*)(ws + 268959744);
  float*          mm   = (float*)(ws + 269484032);
  float*          out  = (float*)d_out;

  k_prep  <<<1024,  256, 0, stream>>>(we, wf, wg, wh, wbf);
  k_stats <<<16384, 256, 0, stream>>>(front, back, xcm);
  k_gemm1 <<<2048,  256, 0, stream>>>(xcm, wbf, bf, bg, S);
  k_minmax<<<8,     256, 0, stream>>>(S, mm);
  k_gemm2 <<<2048,  256, 0, stream>>>(xcm, wbf, be, bh, S, mm, out);
}

// Round 9
// 542.652 us; speedup vs baseline: 1.4901x; 1.4901x over previous
//
#include <hip/hip_runtime.h>
#include <math.h>

// Problem constants: B=8, C=256, H=W=128
#define PIX 16384                       // H*W
#define TSZ ((size_t)33554432)          // 8*256*16384 elements per tensor

typedef __attribute__((ext_vector_type(8))) short  short8;   // 8 x bf16 (4 VGPRs)
typedef __attribute__((ext_vector_type(4))) float  float4v;
typedef __attribute__((ext_vector_type(4))) unsigned int uint4v;
typedef __attribute__((ext_vector_type(2))) unsigned int uint2v;

__device__ __forceinline__ unsigned short f2bf(float x) {
  unsigned int u = __float_as_uint(x);
  u += 0x7fffu + ((u >> 16) & 1u);      // round-to-nearest-even
  return (unsigned short)(u >> 16);
}
__device__ __forceinline__ float bf2f(unsigned short h) {
  return __uint_as_float(((unsigned int)h) << 16);
}
// pack two fp32 -> (bf16(hi)<<16)|bf16(lo) via v_perm_b32
__device__ __forceinline__ unsigned int pack_bf2(float lo, float hi) {
  unsigned int ul = __float_as_uint(lo); ul += 0x7fffu + ((ul >> 16) & 1u);
  unsigned int uh = __float_as_uint(hi); uh += 0x7fffu + ((uh >> 16) & 1u);
  return __builtin_amdgcn_perm(uh, ul, 0x07060302u);  // [ul.b2,ul.b3,uh.b2,uh.b3]
}

#define SB0   __builtin_amdgcn_sched_barrier(0)
#define BARR  __builtin_amdgcn_s_barrier()
#define LGKM0 asm volatile("s_waitcnt lgkmcnt(0)" ::: "memory")
#define VMC(n) asm volatile("s_waitcnt vmcnt(" #n ")" ::: "memory")

// ---------------------------------------------------------------------------
// Kernel 0: weights -> bf16, PACKED for lane-linear 1KB wave loads.
// Layout (shorts): wpk[g][i=kstep(8)][wv(4)][im(4)][lane(64)][e(8)]
//   lane=(q<<4)|col;  m = wv*64+im*16+col;  k = i*32+q*8+e
// Conv order: 0=FF(wf), 1=GG(wg), 2=EE(we), 3=HH(wh)
// ---------------------------------------------------------------------------
__global__ __launch_bounds__(256) void k_prep(const float* __restrict__ we,
                                              const float* __restrict__ wf,
                                              const float* __restrict__ wg,
                                              const float* __restrict__ wh,
                                              unsigned short* __restrict__ wbf) {
  int idx = blockIdx.x * 256 + threadIdx.x;      // 0 .. 262143
  int g = idx >> 16, within = idx & 65535;
  const float* src = (g == 0) ? wf : (g == 1) ? wg : (g == 2) ? we : wh;
  int e    = within & 7;
  int lane = (within >> 3) & 63;
  int im   = (within >> 9) & 3;
  int wv   = (within >> 11) & 3;
  int i    = within >> 13;
  int col = lane & 15, q = lane >> 4;
  int m = wv * 64 + im * 16 + col;
  int k = i * 32 + q * 8 + e;
  wbf[idx] = f2bf(src[m * 256 + k]);
}

// ---------------------------------------------------------------------------
// Kernel 1: 7x7 patch stats (zero-padded box sums), normalization, adain.
// (R7 structure kept: no xs LDS, global-direct reads, (256,4), 48 VGPR.)
// Output TILED: xcm[tens][b][pt(256)][k=c(256)][px(64)] bf16.
// ---------------------------------------------------------------------------
__global__ __launch_bounds__(256, 4) void k_stats(const float* __restrict__ front,
                                                  const float* __restrict__ back,
                                                  unsigned short* __restrict__ xcm) {
  int blk = blockIdx.x;
  int s   = blk & 7;            // strip (16 rows)
  int c   = (blk >> 3) & 255;
  int b   = blk >> 11;
  int t   = threadIdx.x;
  int r0  = s * 16;

  __shared__ float2 vspD[16 * 137];        // 17.54 KB; cols 3..130 = -3..130 data, pads zeroed

  size_t planeOff = ((size_t)(b * 256 + c)) * PIX;

  float meanR[8], sdR[8];       // back stats, phase0 -> phase1 carry

  #pragma unroll 1
  for (int phase = 0; phase < 2; ++phase) {     // 0 = back, 1 = front
    const float* src = (phase == 0 ? back : front) + planeOff;
    // ---- vertical 7-tap sliding box sums: global -> registers -> vspD ----
    {
      int col = t & 127;
      int rg  = (t >> 7) * 8;                    // 8 output rows per thread
      const float* colp = src + col;
      float xv[14];                              // rows r0+rg-3 .. r0+rg+10
      #pragma unroll
      for (int j = 0; j < 14; ++j) {
        int g = r0 + rg - 3 + j;
        float v = 0.f;
        if (g >= 0 && g < 128) v = colp[g * 128];
        xv[j] = v;
      }
      float sm = 0.f, s2 = 0.f;
      #pragma unroll
      for (int j = 0; j < 7; ++j) { sm += xv[j]; s2 = fmaf(xv[j], xv[j], s2); }
      vspD[rg * 137 + col + 3] = make_float2(sm, s2);
      #pragma unroll
      for (int o = 1; o < 8; ++o) {
        float vn = xv[o + 6], vo = xv[o - 1];
        sm += vn - vo;
        s2 += vn * vn - vo * vo;
        vspD[(rg + o) * 137 + col + 3] = make_float2(sm, s2);
      }
      // zero pads: array cols 0,1,2 and 131,132,133 for all 16 rows
      if (t < 96) {
        int rr = t & 15;
        int pc = t >> 4;                         // 0..5
        int ac = (pc < 3) ? pc : 128 + pc;       // 0,1,2,131,132,133
        vspD[rr * 137 + ac] = make_float2(0.f, 0.f);
      }
    }
    LGKM0; BARR;
    // ---- horizontal 7-tap sliding window + finalize + DIRECT stores ----
    {
      int r  = t & 15;
      int c0 = (t >> 4) * 8;                     // 8 output cols per thread
      float2 w[14];
      #pragma unroll
      for (int i = 0; i < 14; ++i) w[i] = vspD[r * 137 + c0 + i];
      // center x values, re-read from global (L1-hot: just fetched above)
      float4v x0 = *(const float4v*)(src + (r0 + r) * 128 + c0);
      float4v x1 = *(const float4v*)(src + (r0 + r) * 128 + c0 + 4);
      float xc[8] = {x0[0], x0[1], x0[2], x0[3], x1[0], x1[1], x1[2], x1[3]};
      float sm = 0.f, s2 = 0.f;
      #pragma unroll
      for (int i = 0; i < 7; ++i) { sm += w[i].x; s2 += w[i].y; }
      float nrmv[8], hv[8];
      #pragma unroll
      for (int o = 0; o < 8; ++o) {
        float mean = sm * (1.f / 49.f);
        float var  = (s2 - sm * mean) * (1.f / 48.f);   // (s2 - s^2/49)/48
        var = var > 0.f ? var : 0.f;
        float sd = __builtin_amdgcn_sqrtf(var);
        float x  = xc[o];
        float nrm = (x - mean) * __builtin_amdgcn_rcpf(sd + 1e-8f);
        if (phase == 0) { meanR[o] = mean; sdR[o] = sd; hv[o] = x; }
        else            { hv[o] = nrm * sdR[o] + meanR[o]; }
        nrmv[o] = nrm;
        if (o < 7) { sm += w[o + 7].x - w[o].x; s2 += w[o + 7].y - w[o].y; }
      }
      uint4v nv  = (uint4v){pack_bf2(nrmv[0], nrmv[1]), pack_bf2(nrmv[2], nrmv[3]),
                            pack_bf2(nrmv[4], nrmv[5]), pack_bf2(nrmv[6], nrmv[7])};
      uint4v hvv = (uint4v){pack_bf2(hv[0], hv[1]), pack_bf2(hv[2], hv[3]),
                            pack_bf2(hv[4], hv[5]), pack_bf2(hv[6], hv[7])};
      // tiled store: p -> (pt=p>>6, pxi=p&63); addr = ((b*256+pt)*256+c)*64+pxi
      int p = (r0 + r) * 128 + c0;
      size_t gb2 = (((size_t)(b * 256 + (p >> 6))) * 256 + c) * 64 + (p & 63);
      int tn0 = (phase == 0) ? 1 : 0;
      int tn1 = (phase == 0) ? 3 : 2;
      *(uint4v*)(xcm + (size_t)tn0 * TSZ + gb2) = nv;
      *(uint4v*)(xcm + (size_t)tn1 * TSZ + gb2) = hvv;
    }
    LGKM0; BARR;   // all vspD reads done; next phase may overwrite
  }
}

// ---------------------------------------------------------------------------
// GEMM machinery. R9: af rotation reduced 3-deep -> 2-deep (A prefetched 1
// step ahead; weights are L2-hot so ~1 step covers the latency). Saves 16
// VGPR so the dual-accumulator kernels fit the 3-waves/EU unified-file cap
// (512/3 = 170; acc 128 in AGPR + ~36 arch). vmcnt table re-derived:
// at step i the FIFO after A(i) holds stage(i+3) + A(i+1) -> VN=5 steady,
// 4 in tail steps, 0 last. Slot mapping (tile i -> slot i%5) unchanged.
// ---------------------------------------------------------------------------
__device__ __forceinline__ void stage_tile(const unsigned short* __restrict__ Xt,
                                           int k0, int t,
                                           unsigned short* dst) {
  // LDS 16B-chunk t holds subtile element: k = (t>>5)*4 + ((t&7)>>1),
  // px = ((t>>3)&3)*16 + (t&1)*8.  Source tile is contiguous [k][px] 4KB.
  int kk = ((t >> 5) << 2) + ((t & 7) >> 1);
  int px = (((t >> 3) & 3) << 4) + ((t & 1) << 3);
  const unsigned short* src = Xt + (size_t)(k0 << 6) + (kk << 6) + px;
  typedef const __attribute__((address_space(1))) unsigned int GUI;
  typedef __attribute__((address_space(3))) unsigned int LUI;
  __builtin_amdgcn_global_load_lds((GUI*)(unsigned long long)src,
                                   (LUI*)(unsigned)(unsigned long long)(dst + t * 8),
                                   16, 0, 0);
}

// packed weights: af[S][im] <- Wr + I*8192 + im*512  (lane-linear 1KB/instr)
#define LOADA(S, I) {                                           \
  af[S][0] = *(const short8*)(Wr + (I) * 8192 + 0 * 512);       \
  af[S][1] = *(const short8*)(Wr + (I) * 8192 + 1 * 512);       \
  af[S][2] = *(const short8*)(Wr + (I) * 8192 + 2 * 512);       \
  af[S][3] = *(const short8*)(Wr + (I) * 8192 + 3 * 512); }

#define TR8(O0,O1,O2,O3,O4,O5,O6,O7)                                              \
  asm volatile("ds_read_b64_tr_b16 %0, %1 offset:" #O0 : "=v"(r0) : "v"(tra));    \
  asm volatile("ds_read_b64_tr_b16 %0, %1 offset:" #O1 : "=v"(r1) : "v"(tra));    \
  asm volatile("ds_read_b64_tr_b16 %0, %1 offset:" #O2 : "=v"(r2) : "v"(tra));    \
  asm volatile("ds_read_b64_tr_b16 %0, %1 offset:" #O3 : "=v"(r3) : "v"(tra));    \
  asm volatile("ds_read_b64_tr_b16 %0, %1 offset:" #O4 : "=v"(r4) : "v"(tra));    \
  asm volatile("ds_read_b64_tr_b16 %0, %1 offset:" #O5 : "=v"(r5) : "v"(tra));    \
  asm volatile("ds_read_b64_tr_b16 %0, %1 offset:" #O6 : "=v"(r6) : "v"(tra));    \
  asm volatile("ds_read_b64_tr_b16 %0, %1 offset:" #O7 : "=v"(r7) : "v"(tra));

#define DOMFMA(MS) {                                                        \
  union BU { unsigned u[4]; short8 s; } bu0, bu1, bu2, bu3;                 \
  bu0.u[0]=r0[0]; bu0.u[1]=r0[1]; bu0.u[2]=r1[0]; bu0.u[3]=r1[1];           \
  bu1.u[0]=r2[0]; bu1.u[1]=r2[1]; bu1.u[2]=r3[0]; bu1.u[3]=r3[1];           \
  bu2.u[0]=r4[0]; bu2.u[1]=r4[1]; bu2.u[2]=r5[0]; bu2.u[3]=r5[1];           \
  bu3.u[0]=r6[0]; bu3.u[1]=r6[1]; bu3.u[2]=r7[0]; bu3.u[3]=r7[1];           \
  short8 bv0 = bu0.s, bv1 = bu1.s, bv2 = bu2.s, bv3 = bu3.s;                \
  _Pragma("unroll")                                                         \
  for (int im = 0; im < 4; ++im) {                                          \
    acc[0][im] = __builtin_amdgcn_mfma_f32_16x16x32_bf16(af[MS][im], bv0, acc[0][im], 0, 0, 0); \
    acc[1][im] = __builtin_amdgcn_mfma_f32_16x16x32_bf16(af[MS][im], bv1, acc[1][im], 0, 0, 0); \
    acc[2][im] = __builtin_amdgcn_mfma_f32_16x16x32_bf16(af[MS][im], bv2, acc[2][im], 0, 0, 0); \
    acc[3][im] = __builtin_amdgcn_mfma_f32_16x16x32_bf16(af[MS][im], bv3, acc[3][im], 0, 0, 0); \
  } }

// one K-step: optional stage (depth-3), optional A prefetch (1 ahead),
// counted vmcnt, barrier, tr-reads of buf i, MFMA.
#define GSTEP(VN, DOSTAGE, K0, SLOT, DOA, AS, AI, MS, O0,O1,O2,O3,O4,O5,O6,O7) \
  SB0;                                                                          \
  if (DOSTAGE) stage_tile(X, K0, t, xt + (SLOT) * 2048);                        \
  SB0;                                                                          \
  if (DOA) LOADA(AS, AI);                                                       \
  SB0;                                                                          \
  VMC(VN);                                                                      \
  SB0; BARR; SB0;                                                               \
  TR8(O0,O1,O2,O3,O4,O5,O6,O7);                                                 \
  LGKM0; SB0;                                                                   \
  DOMFMA(MS);

__device__ __forceinline__ void gemm_pipe(const unsigned short* __restrict__ X,
                                          const unsigned short* __restrict__ Wm,
                                          unsigned short* xt, unsigned xbase,
                                          int mbase, int lane, int t,
                                          float4v acc[4][4]) {
  unsigned tra = xbase + (unsigned)((((lane >> 4)) << 10) + ((lane & 15) << 3));
  // packed weights: Wr = Wm + wv*2048 + lane*8
  const unsigned short* __restrict__ Wr = Wm + ((mbase >> 6) << 11) + lane * 8;

  short8 af[2][4];
  uint2v r0, r1, r2, r3, r4, r5, r6, r7;

  #pragma unroll
  for (int in = 0; in < 4; ++in)
    #pragma unroll
    for (int im = 0; im < 4; ++im)
      acc[in][im] = (float4v){0.f, 0.f, 0.f, 0.f};

  // top barrier: all waves done reading slots of the previous gemm
  SB0; BARR; SB0;
  stage_tile(X,  0, t, xt + 0 * 2048);
  stage_tile(X, 32, t, xt + 1 * 2048);
  stage_tile(X, 64, t, xt + 2 * 2048);
  SB0;
  LOADA(0, 0);
  SB0;

  //     VN  st  K0  slot  A  AS AI MS   tr offsets (slot*4096 + subtile)
  GSTEP( 5,  1,  96,  3,   1, 1, 1, 0,      0,  512,  128,  640,  256,  768,  384,  896)
  GSTEP( 5,  1, 128,  4,   1, 0, 2, 1,   4096, 4608, 4224, 4736, 4352, 4864, 4480, 4992)
  GSTEP( 5,  1, 160,  0,   1, 1, 3, 0,   8192, 8704, 8320, 8832, 8448, 8960, 8576, 9088)
  GSTEP( 5,  1, 192,  1,   1, 0, 4, 1,  12288,12800,12416,12928,12544,13056,12672,13184)
  GSTEP( 5,  1, 224,  2,   1, 1, 5, 0,  16384,16896,16512,17024,16640,17152,16768,17280)
  GSTEP( 4,  0,   0,  0,   1, 0, 6, 1,      0,  512,  128,  640,  256,  768,  384,  896)
  GSTEP( 4,  0,   0,  0,   1, 1, 7, 0,   4096, 4608, 4224, 4736, 4352, 4864, 4480, 4992)
  GSTEP( 0,  0,   0,  0,   0, 0, 0, 1,   8192, 8704, 8320, 8832, 8448, 8960, 8576, 9088)
}

// ---------------------------------------------------------------------------
// Kernel 2a: FF/GG gemms -> cosine similarity S.
// R9: __launch_bounds__(256,3) (3 waves/EU, unified-file cap 170; fits with
// the 2-deep af rotation). R8's (256,4) cap of 128 < acc alone (128) ->
// catastrophic spill (VGPR 64, WRITE +450MB).
// ---------------------------------------------------------------------------
__global__ __launch_bounds__(256, 3) void k_gemm1(const unsigned short* __restrict__ xcm,
                                                  const unsigned short* __restrict__ wbf,
                                                  const float* __restrict__ bFF,
                                                  const float* __restrict__ bGG,
                                                  float* __restrict__ Sout) {
  int blk  = blockIdx.x;
  int b    = blk >> 8;
  int pt   = blk & 255;
  int p0   = pt * 64;
  int t    = threadIdx.x;
  int wv   = t >> 6;
  int lane = t & 63;
  int q    = lane >> 4;
  int mbase = wv * 64;

  __shared__ __align__(16) unsigned short xt[5][2048];   // 20 KB: 5 X buffers
  __shared__ float sred[3 * 64];       // dot, |F|^2, |G|^2 per pixel
  if (t < 192) sred[t] = 0.f;
  __syncthreads();
  unsigned xbase = (unsigned)(unsigned long long)&xt[0][0];

  // contiguous X tile base for this (b, pt): xcm[tens][b][pt][k][px]
  const unsigned short* Xt = xcm + (((size_t)(b * 256 + pt)) << 14);

  float4v aF[4][4], aG[4][4];

  gemm_pipe(Xt + 0 * TSZ, wbf + 0 * 65536, &xt[0][0], xbase, mbase, lane, t, aF);
  gemm_pipe(Xt + 1 * TSZ, wbf + 1 * 65536, &xt[0][0], xbase, mbase, lane, t, aG);
  #pragma unroll
  for (int im = 0; im < 4; ++im) {
    float4v bvF = *(const float4v*)(bFF + mbase + im * 16 + q * 4);
    float4v bvG = *(const float4v*)(bGG + mbase + im * 16 + q * 4);
    #pragma unroll
    for (int in = 0; in < 4; ++in) { aF[in][im] += bvF; aG[in][im] += bvG; }
  }
  // cosine partials: lane-local over 16 m's, then quad shuffle, then LDS
  #pragma unroll
  for (int in = 0; in < 4; ++in) {
    float d = 0.f, nf = 0.f, ng = 0.f;
    #pragma unroll
    for (int im = 0; im < 4; ++im)
      #pragma unroll
      for (int r = 0; r < 4; ++r) {
        float f = aF[in][im][r], g = aG[in][im][r];
        d += f * g; nf += f * f; ng += g * g;
      }
    d  += __shfl_xor(d, 16);  d  += __shfl_xor(d, 32);
    nf += __shfl_xor(nf, 16); nf += __shfl_xor(nf, 32);
    ng += __shfl_xor(ng, 16); ng += __shfl_xor(ng, 32);
    if (lane < 16) {
      atomicAdd(&sred[0 * 64 + in * 16 + lane], d);
      atomicAdd(&sred[1 * 64 + in * 16 + lane], nf);
      atomicAdd(&sred[2 * 64 + in * 16 + lane], ng);
    }
  }
  __syncthreads();
  if (t < 64) {
    float d = sred[t], nf = sred[64 + t], ng = sred[128 + t];
    Sout[(size_t)b * PIX + p0 + t] = d / (sqrtf(nf) * sqrtf(ng));
  }
}

// ---------------------------------------------------------------------------
// Kernel 2b: EE/HH gemms fused with the blend: out = S_n*EE + (1-S_n)*HH.
// R9: __launch_bounds__(256,3) (same rationale as k_gemm1).
// ---------------------------------------------------------------------------
__global__ __launch_bounds__(256, 3) void k_gemm2(const unsigned short* __restrict__ xcm,
                                                  const unsigned short* __restrict__ wbf,
                                                  const float* __restrict__ bEE,
                                                  const float* __restrict__ bHH,
                                                  const float* __restrict__ S,
                                                  const float* __restrict__ mm,
                                                  float* __restrict__ out) {
  int blk  = blockIdx.x;
  int b    = blk >> 8;
  int pt   = blk & 255;
  int p0   = pt * 64;
  int t    = threadIdx.x;
  int wv   = t >> 6;
  int lane = t & 63;
  int col  = lane & 15;
  int q    = lane >> 4;
  int mbase = wv * 64;

  __shared__ __align__(16) unsigned short xt[5][2048];   // 20 KB: 5 X buffers
  unsigned xbase = (unsigned)(unsigned long long)&xt[0][0];

  const unsigned short* Xt = xcm + (((size_t)(b * 256 + pt)) << 14);

  float4v aE[4][4], aH[4][4];

  gemm_pipe(Xt + 2 * TSZ, wbf + 2 * 65536, &xt[0][0], xbase, mbase, lane, t, aE);
  gemm_pipe(Xt + 3 * TSZ, wbf + 3 * 65536, &xt[0][0], xbase, mbase, lane, t, aH);

  float mn = mm[b * 2], mx = mm[b * 2 + 1];
  float inv = 1.f / (mx - mn);
  float sn[4];
  #pragma unroll
  for (int in = 0; in < 4; ++in)
    sn[in] = (S[(size_t)b * PIX + p0 + in * 16 + col] - mn) * inv;

  #pragma unroll
  for (int im = 0; im < 4; ++im) {
    float4v bvE = *(const float4v*)(bEE + mbase + im * 16 + q * 4);
    float4v bvH = *(const float4v*)(bHH + mbase + im * 16 + q * 4);
    #pragma unroll
    for (int in = 0; in < 4; ++in)
      #pragma unroll
      for (int r = 0; r < 4; ++r) {
        int m = mbase + im * 16 + q * 4 + r;
        float e = aE[in][im][r] + bvE[r];
        float h = aH[in][im][r] + bvH[r];
        out[((size_t)(b * 256 + m)) * PIX + p0 + in * 16 + col] = h + sn[in] * (e - h);
      }
  }
}

// ---------------------------------------------------------------------------
// Kernel 3: per-batch min/max of S (one block per batch)
// ---------------------------------------------------------------------------
__global__ __launch_bounds__(256) void k_minmax(const float* __restrict__ S,
                                                float* __restrict__ mm) {
  int b = blockIdx.x, t = threadIdx.x;
  const float* sp = S + (size_t)b * PIX;
  float mn = 3.0e38f, mx = -3.0e38f;
  for (int i = t; i < PIX; i += 256) { float v = sp[i]; mn = fminf(mn, v); mx = fmaxf(mx, v); }
  #pragma unroll
  for (int o = 32; o >= 1; o >>= 1) {
    mn = fminf(mn, __shfl_xor(mn, o));
    mx = fmaxf(mx, __shfl_xor(mx, o));
  }
  __shared__ float smn[4], smx[4];
  if ((t & 63) == 0) { smn[t >> 6] = mn; smx[t >> 6] = mx; }
  __syncthreads();
  if (t == 0) {
    mn = fminf(fminf(smn[0], smn[1]), fminf(smn[2], smn[3]));
    mx = fmaxf(fmaxf(smx[0], smx[1]), fmaxf(smx[2], smx[3]));
    mm[b * 2] = mn; mm[b * 2 + 1] = mx;
  }
}

// ---------------------------------------------------------------------------
// Workspace layout (bytes):
//   0          : xcm   4 tensors bf16 (tiled)    = 268,435,456
//   268435456  : wbf   4x256x256 bf16 (packed)   =     524,288
//   268959744  : S     fp32 8x16384              =     524,288
//   269484032  : mm    fp32 8x2                  =          64
// total ~269.5 MB
// ---------------------------------------------------------------------------
extern "C" void kernel_launch(void* const* d_in, const int* in_sizes, int n_in,
                              void* d_out, int out_size, void* d_ws, size_t ws_size,
                              hipStream_t stream) {
  const float* front = (const float*)d_in[0];
  const float* back  = (const float*)d_in[1];
  // d_in[2] = mask (unused by reference)
  const float* we = (const float*)d_in[3];
  const float* be = (const float*)d_in[4];
  const float* wf = (const float*)d_in[5];
  const float* bf = (const float*)d_in[6];
  const float* wg = (const float*)d_in[7];
  const float* bg = (const float*)d_in[8];
  const float* wh = (const float*)d_in[9];
  const float* bh = (const float*)d_in[10];

  char* ws = (char*)d_ws;
  unsigned short* xcm  = (unsigned short*)(ws);
  unsigned short* wbf  = (unsigned short*)(ws + 268435456);
  float*          S    = (float*)(ws + 268959744);
  float*          mm   = (float*)(ws + 269484032);
  float*          out  = (float*)d_out;

  k_prep  <<<1024,  256, 0, stream>>>(we, wf, wg, wh, wbf);
  k_stats <<<16384, 256, 0, stream>>>(front, back, xcm);
  k_gemm1 <<<2048,  256, 0, stream>>>(xcm, wbf, bf, bg, S);
  k_minmax<<<8,     256, 0, stream>>>(S, mm);
  k_gemm2 <<<2048,  256, 0, stream>>>(xcm, wbf, be, bh, S, mm, out);
}

// Round 10
// 511.476 us; speedup vs baseline: 1.5809x; 1.0610x over previous
//
#include <hip/hip_runtime.h>
#include <math.h>

// Problem constants: B=8, C=256, H=W=128
#define PIX 16384                       // H*W
#define TSZ ((size_t)33554432)          // 8*256*16384 elements per tensor

typedef __attribute__((ext_vector_type(8))) short  short8;   // 8 x bf16 (4 VGPRs)
typedef __attribute__((ext_vector_type(4))) float  float4v;
typedef __attribute__((ext_vector_type(4))) unsigned int uint4v;
typedef __attribute__((ext_vector_type(2))) unsigned int uint2v;

__device__ __forceinline__ unsigned short f2bf(float x) {
  unsigned int u = __float_as_uint(x);
  u += 0x7fffu + ((u >> 16) & 1u);      // round-to-nearest-even
  return (unsigned short)(u >> 16);
}
__device__ __forceinline__ float bf2f(unsigned short h) {
  return __uint_as_float(((unsigned int)h) << 16);
}
// pack two fp32 -> (bf16(hi)<<16)|bf16(lo) via v_perm_b32
__device__ __forceinline__ unsigned int pack_bf2(float lo, float hi) {
  unsigned int ul = __float_as_uint(lo); ul += 0x7fffu + ((ul >> 16) & 1u);
  unsigned int uh = __float_as_uint(hi); uh += 0x7fffu + ((uh >> 16) & 1u);
  return __builtin_amdgcn_perm(uh, ul, 0x07060302u);  // [ul.b2,ul.b3,uh.b2,uh.b3]
}

#define SB0   __builtin_amdgcn_sched_barrier(0)
#define BARR  __builtin_amdgcn_s_barrier()
#define LGKM0 asm volatile("s_waitcnt lgkmcnt(0)" ::: "memory")
#define VMC(n) asm volatile("s_waitcnt vmcnt(" #n ")" ::: "memory")

// ---------------------------------------------------------------------------
// Kernel 0: weights -> bf16, PACKED for lane-linear 1KB wave loads.
// Layout (shorts): wpk[g][i=kstep(8)][wv(4)][im(4)][lane(64)][e(8)]
//   lane=(q<<4)|col;  m = wv*64+im*16+col;  k = i*32+q*8+e
// Conv order: 0=FF(wf), 1=GG(wg), 2=EE(we), 3=HH(wh)
// ---------------------------------------------------------------------------
__global__ __launch_bounds__(256) void k_prep(const float* __restrict__ we,
                                              const float* __restrict__ wf,
                                              const float* __restrict__ wg,
                                              const float* __restrict__ wh,
                                              unsigned short* __restrict__ wbf) {
  int idx = blockIdx.x * 256 + threadIdx.x;      // 0 .. 262143
  int g = idx >> 16, within = idx & 65535;
  const float* src = (g == 0) ? wf : (g == 1) ? wg : (g == 2) ? we : wh;
  int e    = within & 7;
  int lane = (within >> 3) & 63;
  int im   = (within >> 9) & 3;
  int wv   = (within >> 11) & 3;
  int i    = within >> 13;
  int col = lane & 15, q = lane >> 4;
  int m = wv * 64 + im * 16 + col;
  int k = i * 32 + q * 8 + e;
  wbf[idx] = f2bf(src[m * 256 + k]);
}

// ---------------------------------------------------------------------------
// Kernel 1: 7x7 patch stats (zero-padded box sums), normalization, adain.
// (R7 structure kept: no xs LDS, global-direct reads, (256,4), 48 VGPR.)
// Output TILED: xcm[tens][b][pt(256)][k=c(256)][px(64)] bf16.
// ---------------------------------------------------------------------------
__global__ __launch_bounds__(256, 4) void k_stats(const float* __restrict__ front,
                                                  const float* __restrict__ back,
                                                  unsigned short* __restrict__ xcm) {
  int blk = blockIdx.x;
  int s   = blk & 7;            // strip (16 rows)
  int c   = (blk >> 3) & 255;
  int b   = blk >> 11;
  int t   = threadIdx.x;
  int r0  = s * 16;

  __shared__ float2 vspD[16 * 137];        // 17.54 KB; cols 3..130 = -3..130 data, pads zeroed

  size_t planeOff = ((size_t)(b * 256 + c)) * PIX;

  float meanR[8], sdR[8];       // back stats, phase0 -> phase1 carry

  #pragma unroll 1
  for (int phase = 0; phase < 2; ++phase) {     // 0 = back, 1 = front
    const float* src = (phase == 0 ? back : front) + planeOff;
    // ---- vertical 7-tap sliding box sums: global -> registers -> vspD ----
    {
      int col = t & 127;
      int rg  = (t >> 7) * 8;                    // 8 output rows per thread
      const float* colp = src + col;
      float xv[14];                              // rows r0+rg-3 .. r0+rg+10
      #pragma unroll
      for (int j = 0; j < 14; ++j) {
        int g = r0 + rg - 3 + j;
        float v = 0.f;
        if (g >= 0 && g < 128) v = colp[g * 128];
        xv[j] = v;
      }
      float sm = 0.f, s2 = 0.f;
      #pragma unroll
      for (int j = 0; j < 7; ++j) { sm += xv[j]; s2 = fmaf(xv[j], xv[j], s2); }
      vspD[rg * 137 + col + 3] = make_float2(sm, s2);
      #pragma unroll
      for (int o = 1; o < 8; ++o) {
        float vn = xv[o + 6], vo = xv[o - 1];
        sm += vn - vo;
        s2 += vn * vn - vo * vo;
        vspD[(rg + o) * 137 + col + 3] = make_float2(sm, s2);
      }
      // zero pads: array cols 0,1,2 and 131,132,133 for all 16 rows
      if (t < 96) {
        int rr = t & 15;
        int pc = t >> 4;                         // 0..5
        int ac = (pc < 3) ? pc : 128 + pc;       // 0,1,2,131,132,133
        vspD[rr * 137 + ac] = make_float2(0.f, 0.f);
      }
    }
    LGKM0; BARR;
    // ---- horizontal 7-tap sliding window + finalize + DIRECT stores ----
    {
      int r  = t & 15;
      int c0 = (t >> 4) * 8;                     // 8 output cols per thread
      float2 w[14];
      #pragma unroll
      for (int i = 0; i < 14; ++i) w[i] = vspD[r * 137 + c0 + i];
      // center x values, re-read from global (L1-hot: just fetched above)
      float4v x0 = *(const float4v*)(src + (r0 + r) * 128 + c0);
      float4v x1 = *(const float4v*)(src + (r0 + r) * 128 + c0 + 4);
      float xc[8] = {x0[0], x0[1], x0[2], x0[3], x1[0], x1[1], x1[2], x1[3]};
      float sm = 0.f, s2 = 0.f;
      #pragma unroll
      for (int i = 0; i < 7; ++i) { sm += w[i].x; s2 += w[i].y; }
      float nrmv[8], hv[8];
      #pragma unroll
      for (int o = 0; o < 8; ++o) {
        float mean = sm * (1.f / 49.f);
        float var  = (s2 - sm * mean) * (1.f / 48.f);   // (s2 - s^2/49)/48
        var = var > 0.f ? var : 0.f;
        float sd = __builtin_amdgcn_sqrtf(var);
        float x  = xc[o];
        float nrm = (x - mean) * __builtin_amdgcn_rcpf(sd + 1e-8f);
        if (phase == 0) { meanR[o] = mean; sdR[o] = sd; hv[o] = x; }
        else            { hv[o] = nrm * sdR[o] + meanR[o]; }
        nrmv[o] = nrm;
        if (o < 7) { sm += w[o + 7].x - w[o].x; s2 += w[o + 7].y - w[o].y; }
      }
      uint4v nv  = (uint4v){pack_bf2(nrmv[0], nrmv[1]), pack_bf2(nrmv[2], nrmv[3]),
                            pack_bf2(nrmv[4], nrmv[5]), pack_bf2(nrmv[6], nrmv[7])};
      uint4v hvv = (uint4v){pack_bf2(hv[0], hv[1]), pack_bf2(hv[2], hv[3]),
                            pack_bf2(hv[4], hv[5]), pack_bf2(hv[6], hv[7])};
      // tiled store: p -> (pt=p>>6, pxi=p&63); addr = ((b*256+pt)*256+c)*64+pxi
      int p = (r0 + r) * 128 + c0;
      size_t gb2 = (((size_t)(b * 256 + (p >> 6))) * 256 + c) * 64 + (p & 63);
      int tn0 = (phase == 0) ? 1 : 0;
      int tn1 = (phase == 0) ? 3 : 2;
      *(uint4v*)(xcm + (size_t)tn0 * TSZ + gb2) = nv;
      *(uint4v*)(xcm + (size_t)tn1 * TSZ + gb2) = hvv;
    }
    LGKM0; BARR;   // all vspD reads done; next phase may overwrite
  }
}

// ---------------------------------------------------------------------------
// GEMM machinery. R10: BK=64 SUPERSTEP at (256,2).
//  - Revert to 2 blocks/CU: this structure needs ~216 unified regs (acc 128
//    AGPR + ~88 arch); 3 waves/EU (cap 170) spilled in R8/R9.
//  - 8 LDS slots (32 KB), tiles 0..7 -> slots 0..7 (no wraparound; cross-pipe
//    reuse protected by the top barrier + each wave's lgkm-drained tr reads).
//  - Two K-tiles per barrier section: barriers/pipe 9 -> 5 (m233: the
//    stage+vmcnt+barrier toll dominates 2-phase loops).
//  - vmcnt audit (FIFO): prologue S0..S3. SS0: P0(8),S4,S5 -> need S0,S1,P0
//    -> VMC(2). SS1: P1(8),S6,S7 -> need S2,S3,P1 -> VMC(2). SS2: P2(8) ->
//    VMC(0) (tail; S6,S7 ~1 superstep old). SS3: P3(8) -> VMC(0).
//    A-pair issued BEFORE the stage pair so VMC(2) retires A while leaving
//    the fresh HBM stages in flight.
// ---------------------------------------------------------------------------
__device__ __forceinline__ void stage_tile(const unsigned short* __restrict__ Xt,
                                           int k0, int t,
                                           unsigned short* dst) {
  // LDS 16B-chunk t holds subtile element: k = (t>>5)*4 + ((t&7)>>1),
  // px = ((t>>3)&3)*16 + (t&1)*8.  Source tile is contiguous [k][px] 4KB.
  int kk = ((t >> 5) << 2) + ((t & 7) >> 1);
  int px = (((t >> 3) & 3) << 4) + ((t & 1) << 3);
  const unsigned short* src = Xt + (size_t)(k0 << 6) + (kk << 6) + px;
  typedef const __attribute__((address_space(1))) unsigned int GUI;
  typedef __attribute__((address_space(3))) unsigned int LUI;
  __builtin_amdgcn_global_load_lds((GUI*)(unsigned long long)src,
                                   (LUI*)(unsigned)(unsigned long long)(dst + t * 8),
                                   16, 0, 0);
}

// packed weights: af[S][im] <- Wr + I*8192 + im*512  (lane-linear 1KB/instr)
#define LOADA(S, I) {                                           \
  af[S][0] = *(const short8*)(Wr + (I) * 8192 + 0 * 512);       \
  af[S][1] = *(const short8*)(Wr + (I) * 8192 + 1 * 512);       \
  af[S][2] = *(const short8*)(Wr + (I) * 8192 + 2 * 512);       \
  af[S][3] = *(const short8*)(Wr + (I) * 8192 + 3 * 512); }

#define TR8(O0,O1,O2,O3,O4,O5,O6,O7)                                              \
  asm volatile("ds_read_b64_tr_b16 %0, %1 offset:" #O0 : "=v"(r0) : "v"(tra));    \
  asm volatile("ds_read_b64_tr_b16 %0, %1 offset:" #O1 : "=v"(r1) : "v"(tra));    \
  asm volatile("ds_read_b64_tr_b16 %0, %1 offset:" #O2 : "=v"(r2) : "v"(tra));    \
  asm volatile("ds_read_b64_tr_b16 %0, %1 offset:" #O3 : "=v"(r3) : "v"(tra));    \
  asm volatile("ds_read_b64_tr_b16 %0, %1 offset:" #O4 : "=v"(r4) : "v"(tra));    \
  asm volatile("ds_read_b64_tr_b16 %0, %1 offset:" #O5 : "=v"(r5) : "v"(tra));    \
  asm volatile("ds_read_b64_tr_b16 %0, %1 offset:" #O6 : "=v"(r6) : "v"(tra));    \
  asm volatile("ds_read_b64_tr_b16 %0, %1 offset:" #O7 : "=v"(r7) : "v"(tra));

#define DOMFMA(MS) {                                                        \
  union BU { unsigned u[4]; short8 s; } bu0, bu1, bu2, bu3;                 \
  bu0.u[0]=r0[0]; bu0.u[1]=r0[1]; bu0.u[2]=r1[0]; bu0.u[3]=r1[1];           \
  bu1.u[0]=r2[0]; bu1.u[1]=r2[1]; bu1.u[2]=r3[0]; bu1.u[3]=r3[1];           \
  bu2.u[0]=r4[0]; bu2.u[1]=r4[1]; bu2.u[2]=r5[0]; bu2.u[3]=r5[1];           \
  bu3.u[0]=r6[0]; bu3.u[1]=r6[1]; bu3.u[2]=r7[0]; bu3.u[3]=r7[1];           \
  short8 bv0 = bu0.s, bv1 = bu1.s, bv2 = bu2.s, bv3 = bu3.s;                \
  _Pragma("unroll")                                                         \
  for (int im = 0; im < 4; ++im) {                                          \
    acc[0][im] = __builtin_amdgcn_mfma_f32_16x16x32_bf16(af[MS][im], bv0, acc[0][im], 0, 0, 0); \
    acc[1][im] = __builtin_amdgcn_mfma_f32_16x16x32_bf16(af[MS][im], bv1, acc[1][im], 0, 0, 0); \
    acc[2][im] = __builtin_amdgcn_mfma_f32_16x16x32_bf16(af[MS][im], bv2, acc[2][im], 0, 0, 0); \
    acc[3][im] = __builtin_amdgcn_mfma_f32_16x16x32_bf16(af[MS][im], bv3, acc[3][im], 0, 0, 0); \
  } }

__device__ __forceinline__ void gemm_pipe(const unsigned short* __restrict__ X,
                                          const unsigned short* __restrict__ Wm,
                                          unsigned short* xt, unsigned xbase,
                                          int mbase, int lane, int t,
                                          float4v acc[4][4]) {
  unsigned tra = xbase + (unsigned)((((lane >> 4)) << 10) + ((lane & 15) << 3));
  // packed weights: Wr = Wm + wv*2048 + lane*8
  const unsigned short* __restrict__ Wr = Wm + ((mbase >> 6) << 11) + lane * 8;

  short8 af[2][4];
  uint2v r0, r1, r2, r3, r4, r5, r6, r7;

  #pragma unroll
  for (int in = 0; in < 4; ++in)
    #pragma unroll
    for (int im = 0; im < 4; ++im)
      acc[in][im] = (float4v){0.f, 0.f, 0.f, 0.f};

  // top barrier: all waves done reading slots of the previous gemm
  SB0; BARR; SB0;
  stage_tile(X,   0, t, xt + 0 * 2048);
  stage_tile(X,  32, t, xt + 1 * 2048);
  stage_tile(X,  64, t, xt + 2 * 2048);
  stage_tile(X,  96, t, xt + 3 * 2048);
  SB0;

  // ---- SS0: tiles 0,1 ----
  LOADA(0, 0); LOADA(1, 1);
  SB0;
  stage_tile(X, 128, t, xt + 4 * 2048);
  stage_tile(X, 160, t, xt + 5 * 2048);
  SB0;
  VMC(2); SB0; BARR; SB0;
  TR8(    0,   512,   128,   640,   256,   768,   384,   896); LGKM0; SB0; DOMFMA(0);
  TR8( 4096,  4608,  4224,  4736,  4352,  4864,  4480,  4992); LGKM0; SB0; DOMFMA(1);

  // ---- SS1: tiles 2,3 ----
  SB0;
  LOADA(0, 2); LOADA(1, 3);
  SB0;
  stage_tile(X, 192, t, xt + 6 * 2048);
  stage_tile(X, 224, t, xt + 7 * 2048);
  SB0;
  VMC(2); SB0; BARR; SB0;
  TR8( 8192,  8704,  8320,  8832,  8448,  8960,  8576,  9088); LGKM0; SB0; DOMFMA(0);
  TR8(12288, 12800, 12416, 12928, 12544, 13056, 12672, 13184); LGKM0; SB0; DOMFMA(1);

  // ---- SS2: tiles 4,5 ----
  SB0;
  LOADA(0, 4); LOADA(1, 5);
  SB0;
  VMC(0); SB0; BARR; SB0;
  TR8(16384, 16896, 16512, 17024, 16640, 17152, 16768, 17280); LGKM0; SB0; DOMFMA(0);
  TR8(20480, 20992, 20608, 21120, 20736, 21248, 20864, 21376); LGKM0; SB0; DOMFMA(1);

  // ---- SS3: tiles 6,7 ----
  SB0;
  LOADA(0, 6); LOADA(1, 7);
  SB0;
  VMC(0); SB0; BARR; SB0;
  TR8(24576, 25088, 24704, 25216, 24832, 25344, 24960, 25472); LGKM0; SB0; DOMFMA(0);
  TR8(28672, 29184, 28800, 29312, 28928, 29440, 29056, 29568); LGKM0; SB0; DOMFMA(1);
}

// ---------------------------------------------------------------------------
// Kernel 2a: FF/GG gemms -> cosine similarity S.  (256,2): no spill.
// ---------------------------------------------------------------------------
__global__ __launch_bounds__(256, 2) void k_gemm1(const unsigned short* __restrict__ xcm,
                                                  const unsigned short* __restrict__ wbf,
                                                  const float* __restrict__ bFF,
                                                  const float* __restrict__ bGG,
                                                  float* __restrict__ Sout) {
  int blk  = blockIdx.x;
  int b    = blk >> 8;
  int pt   = blk & 255;
  int p0   = pt * 64;
  int t    = threadIdx.x;
  int wv   = t >> 6;
  int lane = t & 63;
  int q    = lane >> 4;
  int mbase = wv * 64;

  __shared__ __align__(16) unsigned short xt[8][2048];   // 32 KB: 8 X slots
  __shared__ float sred[3 * 64];       // dot, |F|^2, |G|^2 per pixel
  if (t < 192) sred[t] = 0.f;
  __syncthreads();
  unsigned xbase = (unsigned)(unsigned long long)&xt[0][0];

  // contiguous X tile base for this (b, pt): xcm[tens][b][pt][k][px]
  const unsigned short* Xt = xcm + (((size_t)(b * 256 + pt)) << 14);

  float4v aF[4][4], aG[4][4];

  gemm_pipe(Xt + 0 * TSZ, wbf + 0 * 65536, &xt[0][0], xbase, mbase, lane, t, aF);
  gemm_pipe(Xt + 1 * TSZ, wbf + 1 * 65536, &xt[0][0], xbase, mbase, lane, t, aG);
  #pragma unroll
  for (int im = 0; im < 4; ++im) {
    float4v bvF = *(const float4v*)(bFF + mbase + im * 16 + q * 4);
    float4v bvG = *(const float4v*)(bGG + mbase + im * 16 + q * 4);
    #pragma unroll
    for (int in = 0; in < 4; ++in) { aF[in][im] += bvF; aG[in][im] += bvG; }
  }
  // cosine partials: lane-local over 16 m's, then quad shuffle, then LDS
  #pragma unroll
  for (int in = 0; in < 4; ++in) {
    float d = 0.f, nf = 0.f, ng = 0.f;
    #pragma unroll
    for (int im = 0; im < 4; ++im)
      #pragma unroll
      for (int r = 0; r < 4; ++r) {
        float f = aF[in][im][r], g = aG[in][im][r];
        d += f * g; nf += f * f; ng += g * g;
      }
    d  += __shfl_xor(d, 16);  d  += __shfl_xor(d, 32);
    nf += __shfl_xor(nf, 16); nf += __shfl_xor(nf, 32);
    ng += __shfl_xor(ng, 16); ng += __shfl_xor(ng, 32);
    if (lane < 16) {
      atomicAdd(&sred[0 * 64 + in * 16 + lane], d);
      atomicAdd(&sred[1 * 64 + in * 16 + lane], nf);
      atomicAdd(&sred[2 * 64 + in * 16 + lane], ng);
    }
  }
  __syncthreads();
  if (t < 64) {
    float d = sred[t], nf = sred[64 + t], ng = sred[128 + t];
    Sout[(size_t)b * PIX + p0 + t] = d / (sqrtf(nf) * sqrtf(ng));
  }
}

// ---------------------------------------------------------------------------
// Kernel 2b: EE/HH gemms fused with the blend: out = S_n*EE + (1-S_n)*HH.
// ---------------------------------------------------------------------------
__global__ __launch_bounds__(256, 2) void k_gemm2(const unsigned short* __restrict__ xcm,
                                                  const unsigned short* __restrict__ wbf,
                                                  const float* __restrict__ bEE,
                                                  const float* __restrict__ bHH,
                                                  const float* __restrict__ S,
                                                  const float* __restrict__ mm,
                                                  float* __restrict__ out) {
  int blk  = blockIdx.x;
  int b    = blk >> 8;
  int pt   = blk & 255;
  int p0   = pt * 64;
  int t    = threadIdx.x;
  int wv   = t >> 6;
  int lane = t & 63;
  int col  = lane & 15;
  int q    = lane >> 4;
  int mbase = wv * 64;

  __shared__ __align__(16) unsigned short xt[8][2048];   // 32 KB: 8 X slots
  unsigned xbase = (unsigned)(unsigned long long)&xt[0][0];

  const unsigned short* Xt = xcm + (((size_t)(b * 256 + pt)) << 14);

  float4v aE[4][4], aH[4][4];

  gemm_pipe(Xt + 2 * TSZ, wbf + 2 * 65536, &xt[0][0], xbase, mbase, lane, t, aE);
  gemm_pipe(Xt + 3 * TSZ, wbf + 3 * 65536, &xt[0][0], xbase, mbase, lane, t, aH);

  float mn = mm[b * 2], mx = mm[b * 2 + 1];
  float inv = 1.f / (mx - mn);
  float sn[4];
  #pragma unroll
  for (int in = 0; in < 4; ++in)
    sn[in] = (S[(size_t)b * PIX + p0 + in * 16 + col] - mn) * inv;

  #pragma unroll
  for (int im = 0; im < 4; ++im) {
    float4v bvE = *(const float4v*)(bEE + mbase + im * 16 + q * 4);
    float4v bvH = *(const float4v*)(bHH + mbase + im * 16 + q * 4);
    #pragma unroll
    for (int in = 0; in < 4; ++in)
      #pragma unroll
      for (int r = 0; r < 4; ++r) {
        int m = mbase + im * 16 + q * 4 + r;
        float e = aE[in][im][r] + bvE[r];
        float h = aH[in][im][r] + bvH[r];
        out[((size_t)(b * 256 + m)) * PIX + p0 + in * 16 + col] = h + sn[in] * (e - h);
      }
  }
}

// ---------------------------------------------------------------------------
// Kernel 3: per-batch min/max of S (one block per batch)
// ---------------------------------------------------------------------------
__global__ __launch_bounds__(256) void k_minmax(const float* __restrict__ S,
                                                float* __restrict__ mm) {
  int b = blockIdx.x, t = threadIdx.x;
  const float* sp = S + (size_t)b * PIX;
  float mn = 3.0e38f, mx = -3.0e38f;
  for (int i = t; i < PIX; i += 256) { float v = sp[i]; mn = fminf(mn, v); mx = fmaxf(mx, v); }
  #pragma unroll
  for (int o = 32; o >= 1; o >>= 1) {
    mn = fminf(mn, __shfl_xor(mn, o));
    mx = fmaxf(mx, __shfl_xor(mx, o));
  }
  __shared__ float smn[4], smx[4];
  if ((t & 63) == 0) { smn[t >> 6] = mn; smx[t >> 6] = mx; }
  __syncthreads();
  if (t == 0) {
    mn = fminf(fminf(smn[0], smn[1]), fminf(smn[2], smn[3]));
    mx = fmaxf(fmaxf(smx[0], smx[1]), fmaxf(smx[2], smx[3]));
    mm[b * 2] = mn; mm[b * 2 + 1] = mx;
  }
}

// ---------------------------------------------------------------------------
// Workspace layout (bytes):
//   0          : xcm   4 tensors bf16 (tiled)    = 268,435,456
//   268435456  : wbf   4x256x256 bf16 (packed)   =     524,288
//   268959744  : S     fp32 8x16384              =     524,288
//   269484032  : mm    fp32 8x2                  =          64
// total ~269.5 MB
// ---------------------------------------------------------------------------
extern "C" void kernel_launch(void* const* d_in, const int* in_sizes, int n_in,
                              void* d_out, int out_size, void* d_ws, size_t ws_size,
                              hipStream_t stream) {
  const float* front = (const float*)d_in[0];
  const float* back  = (const float*)d_in[1];
  // d_in[2] = mask (unused by reference)
  const float* we = (const float*)d_in[3];
  const float* be = (const float*)d_in[4];
  const float* wf = (const float*)d_in[5];
  const float* bf = (const float*)d_in[6];
  const float* wg = (const float*)d_in[7];
  const float* bg = (const float*)d_in[8];
  const float* wh = (const float*)d_in[9];
  const float* bh = (const float*)d_in[10];

  char* ws = (char*)d_ws;
  unsigned short* xcm  = (unsigned short*)(ws);
  unsigned short* wbf  = (unsigned short*)(ws + 268435456);
  float*          S    = (float*)(ws + 268959744);
  float*          mm   = (float*)(ws + 269484032);
  float*          out  = (float*)d_out;

  k_prep  <<<1024,  256, 0, stream>>>(we, wf, wg, wh, wbf);
  k_stats <<<16384, 256, 0, stream>>>(front, back, xcm);
  k_gemm1 <<<2048,  256, 0, stream>>>(xcm, wbf, bf, bg, S);
  k_minmax<<<8,     256, 0, stream>>>(S, mm);
  k_gemm2 <<<2048,  256, 0, stream>>>(xcm, wbf, be, bh, S, mm, out);
}